// Round 11
// baseline (133.212 us; speedup 1.0000x reference)
//
#include <hip/hip_runtime.h>
#include <math.h>

#define NNODES 50000
#define BB 4
#define FF 64
#define CAP 64   // max random-degree slots per row; Poisson(16) max over 50K nodes ~ 40

#define TROWS 64                             // gemm rows per block (4 waves x 16 rows, MFMA)
#define GEMM_NB ((BB * NNODES) / TROWS)      // 3125 blocks; 3125*256 == 800000 == ES
#define RPB 4                                // gather rows per block (1 per wave)

typedef _Float16 f16;
typedef __attribute__((ext_vector_type(8))) _Float16 f16x8;
typedef __attribute__((ext_vector_type(4))) float f32x4;

// ---------------- helpers ----------------

__device__ inline unsigned short f2bf(float f) {            // round-to-nearest-even
    unsigned u = __float_as_uint(f);
    u += 0x7fffu + ((u >> 16) & 1u);
    return (unsigned short)(u >> 16);
}

__device__ inline void bf4fma(float v, uint2 hv, float& a0, float& a1, float& a2, float& a3) {
    a0 = fmaf(v, __uint_as_float(hv.x << 16),         a0);
    a1 = fmaf(v, __uint_as_float(hv.x & 0xffff0000u), a1);
    a2 = fmaf(v, __uint_as_float(hv.y << 16),         a2);
    a3 = fmaf(v, __uint_as_float(hv.y & 0xffff0000u), a3);
}

// ---------------- fused prep: MFMA gemm + scatter tail ----------------
// h[n][b][f](bf16) = x[b][n][:] @ w via mfma_f32_16x16x32_f16 (f16 input
// rounding 2^-11 is negligible vs the bf16 h-storage rounding 2^-9).
// Fragment layouts (m89-verified family): A lane=(row=l&15, k=8*(l>>4)+j),
// B from W^T in LDS (col=l&15, same k), C (col=l&15, row=4*(l>>4)+reg).
// Each thread's ONE scatter edge is loaded before staging (latency hidden
// under the whole kernel); atomic+store happen at the tail, after which no
// barrier forces a drain.

__global__ __launch_bounds__(256) void prep_kernel(const int* __restrict__ rows,
                                                   const int* __restrict__ cols,
                                                   const float* __restrict__ vals,
                                                   int* __restrict__ cnt,
                                                   unsigned* __restrict__ edata, int ES,
                                                   int cstride,
                                                   const float* __restrict__ x,
                                                   const float* __restrict__ w,
                                                   unsigned short* __restrict__ h) {
    __shared__ f16 xs[64][72];    // 72-pad: 144B rows -> 16B-aligned f16x8 reads, 2-way banks (free)
    __shared__ f16 wt[64][72];    // W transposed: wt[f][k]
    int t = threadIdx.x;
    long rowBase = (long)blockIdx.x * TROWS;

    // early edge load — in flight during staging + mfma
    int e = blockIdx.x * 256 + t;
    bool has_e = (e < ES);
    int r_e = 0, c_e = 0;
    float v_e = 0.f;
    if (has_e) { r_e = rows[e]; c_e = cols[e]; v_e = vals[e]; }

    // stage x (f32 -> f16) and W^T (f32 -> f16) into LDS
    #pragma unroll
    for (int i = 0; i < 4; ++i) {
        int s = t + i * 256;          // 1024 float4 slots: 64 rows x 16
        int r = s >> 4, c4 = s & 15;
        const float4* xp = (const float4*)(x + (rowBase + r) * 64 + c4 * 4);
        float4 xv;
        xv.x = __builtin_nontemporal_load(&xp->x);
        xv.y = __builtin_nontemporal_load(&xp->y);
        xv.z = __builtin_nontemporal_load(&xp->z);
        xv.w = __builtin_nontemporal_load(&xp->w);
        xs[r][c4 * 4 + 0] = (f16)xv.x;
        xs[r][c4 * 4 + 1] = (f16)xv.y;
        xs[r][c4 * 4 + 2] = (f16)xv.z;
        xs[r][c4 * 4 + 3] = (f16)xv.w;
        float4 wv = *(const float4*)(w + r * 64 + c4 * 4);     // w[k=r][f=c4*4..]
        wt[c4 * 4 + 0][r] = (f16)wv.x;
        wt[c4 * 4 + 1][r] = (f16)wv.y;
        wt[c4 * 4 + 2][r] = (f16)wv.z;
        wt[c4 * 4 + 3][r] = (f16)wv.w;
    }
    __syncthreads();

    int wid = t >> 6, l = t & 63;
    int arow = (wid << 4) + (l & 15);
    int kg   = (l >> 4) << 3;
    f16x8 aLo = *(const f16x8*)&xs[arow][kg];
    f16x8 aHi = *(const f16x8*)&xs[arow][32 + kg];
    f32x4 acc[4] = {{0.f,0.f,0.f,0.f},{0.f,0.f,0.f,0.f},{0.f,0.f,0.f,0.f},{0.f,0.f,0.f,0.f}};
    #pragma unroll
    for (int c = 0; c < 4; ++c) {
        f16x8 bLo = *(const f16x8*)&wt[c * 16 + (l & 15)][kg];
        f16x8 bHi = *(const f16x8*)&wt[c * 16 + (l & 15)][32 + kg];
        acc[c] = __builtin_amdgcn_mfma_f32_16x16x32_f16(aLo, bLo, acc[c], 0, 0, 0);
        acc[c] = __builtin_amdgcn_mfma_f32_16x16x32_f16(aHi, bHi, acc[c], 0, 0, 0);
    }

    // store h bf16 into [n][b][f]
    int mloc = (l >> 4) << 2, fcol = l & 15;
    #pragma unroll
    for (int reg = 0; reg < 4; ++reg) {
        long m = rowBase + (wid << 4) + mloc + reg;   // m = b*N + n
        int  b = (int)(m / NNODES);
        int  n = (int)(m - (long)b * NNODES);
        unsigned short* hp = h + ((size_t)n * BB + b) * 64 + fcol;
        #pragma unroll
        for (int c = 0; c < 4; ++c) hp[c * 16] = f2bf(acc[c][reg]);
    }

    // scatter tail (no barrier after -> no vmcnt drain blocks other waves)
    if (has_e) {
        int pos = atomicAdd(&cnt[(size_t)r_e * cstride], 1);
        if (pos < CAP) {
            unsigned p = ((unsigned)f2bf(v_e) << 16) | (unsigned)c_e;
            edata[(size_t)r_e * CAP + pos] = p;
        }
    }
}

// ---------------- out[b,r,:] = ELU(bias + val_self*h[r] + sum_e val*h[col]) ----------------
// one wave per row; lane: b = lane>>4, feature quad fq = lane&15.
// Packed edge list loaded ONCE (masked, coalesced, non-temporal); per iteration
// (col,val) decode from one __shfl broadcast. Inner loop padded to a multiple
// of 8 with zero-val edges so there is NO serial tail.

__global__ __launch_bounds__(256) void gather_kernel(const unsigned short* __restrict__ h,
                                                     const int* __restrict__ cnt,
                                                     const unsigned* __restrict__ edata,
                                                     const float* __restrict__ vals,
                                                     const float* __restrict__ bias,
                                                     float* __restrict__ out,
                                                     int cstride, int ES) {
    int wave = threadIdx.x >> 6;
    int lane = threadIdx.x & 63;
    int r = blockIdx.x * RPB + wave;
    if (r >= NNODES) return;
    int deg = cnt[(size_t)r * cstride];
    if (deg > CAP) deg = CAP;
    int b  = lane >> 4;
    int fq = lane & 15;
    const unsigned short* hb = h + b * 64 + fq * 4;   // lane's base within a node's 256 elems
    unsigned my_p = 0u;
    if (lane < deg) {                                  // masked + NT: stream, don't cache
        const unsigned* ep = &edata[(size_t)r * CAP + lane];
        my_p = __builtin_nontemporal_load(ep);
    }
    // self-loop issued early (independent load in flight during the edge loop)
    float vs = vals[ES + r];
    uint2 hs = *(const uint2*)(hb + (size_t)r * 256);
    float4 b4 = ((const float4*)bias)[fq];

    float a0 = 0.f, a1 = 0.f, a2 = 0.f, a3 = 0.f;
    int dg8 = (deg + 7) & ~7;                          // <= 64
    for (int k = 0; k < dg8; k += 8) {
        unsigned p0 = __shfl(my_p, k,     64), p1 = __shfl(my_p, k + 1, 64);
        unsigned p2 = __shfl(my_p, k + 2, 64), p3 = __shfl(my_p, k + 3, 64);
        unsigned p4 = __shfl(my_p, k + 4, 64), p5 = __shfl(my_p, k + 5, 64);
        unsigned p6 = __shfl(my_p, k + 6, 64), p7 = __shfl(my_p, k + 7, 64);
        uint2 h0 = *(const uint2*)(hb + (size_t)(p0 & 0xFFFFu) * 256);
        uint2 h1 = *(const uint2*)(hb + (size_t)(p1 & 0xFFFFu) * 256);
        uint2 h2 = *(const uint2*)(hb + (size_t)(p2 & 0xFFFFu) * 256);
        uint2 h3 = *(const uint2*)(hb + (size_t)(p3 & 0xFFFFu) * 256);
        uint2 h4 = *(const uint2*)(hb + (size_t)(p4 & 0xFFFFu) * 256);
        uint2 h5 = *(const uint2*)(hb + (size_t)(p5 & 0xFFFFu) * 256);
        uint2 h6 = *(const uint2*)(hb + (size_t)(p6 & 0xFFFFu) * 256);
        uint2 h7 = *(const uint2*)(hb + (size_t)(p7 & 0xFFFFu) * 256);
        bf4fma(__uint_as_float(p0 & 0xFFFF0000u), h0, a0, a1, a2, a3);
        bf4fma(__uint_as_float(p1 & 0xFFFF0000u), h1, a0, a1, a2, a3);
        bf4fma(__uint_as_float(p2 & 0xFFFF0000u), h2, a0, a1, a2, a3);
        bf4fma(__uint_as_float(p3 & 0xFFFF0000u), h3, a0, a1, a2, a3);
        bf4fma(__uint_as_float(p4 & 0xFFFF0000u), h4, a0, a1, a2, a3);
        bf4fma(__uint_as_float(p5 & 0xFFFF0000u), h5, a0, a1, a2, a3);
        bf4fma(__uint_as_float(p6 & 0xFFFF0000u), h6, a0, a1, a2, a3);
        bf4fma(__uint_as_float(p7 & 0xFFFF0000u), h7, a0, a1, a2, a3);
    }
    // self-loop contribution (reference appends self-loops last: val = vals[ES+r])
    bf4fma(vs, hs, a0, a1, a2, a3);
    a0 += b4.x; a1 += b4.y; a2 += b4.z; a3 += b4.w;
    a0 = a0 > 0.f ? a0 : expm1f(a0);
    a1 = a1 > 0.f ? a1 : expm1f(a1);
    a2 = a2 > 0.f ? a2 : expm1f(a2);
    a3 = a3 > 0.f ? a3 : expm1f(a3);
    float4 o = make_float4(a0, a1, a2, a3);
    *(float4*)(out + ((size_t)b * NNODES + r) * 64 + fq * 4) = o;   // plain store (harness-validated buffer)
}

// ---------------- launch ----------------

static inline size_t align256(size_t x) { return (x + 255) & ~(size_t)255; }

extern "C" void kernel_launch(void* const* d_in, const int* in_sizes, int n_in,
                              void* d_out, int out_size, void* d_ws, size_t ws_size,
                              hipStream_t stream) {
    const float* x    = (const float*)d_in[0];
    const float* vals = (const float*)d_in[1];
    const float* w    = (const float*)d_in[2];
    const float* bias = (const float*)d_in[3];
    const int*   rows = (const int*)d_in[4];
    const int*   cols = (const int*)d_in[5];
    float* out = (float*)d_out;
    const int E  = in_sizes[1];
    const int ES = E - NNODES;                       // random edges (self-loops are the last N)

    // cnt padded to one counter per 64B line if workspace allows; fallback stride 1.
    size_t h_b     = align256((size_t)BB * NNODES * FF * sizeof(unsigned short)); // 25.6 MB
    size_t edata_b = align256((size_t)NNODES * CAP * sizeof(unsigned));           // 12.8 MB
    int cstride = 16;
    if (h_b + edata_b + align256((size_t)NNODES * 16 * sizeof(int)) > ws_size) cstride = 1;

    char* ws = (char*)d_ws;
    size_t off = 0;
    unsigned short* h = (unsigned short*)(ws + off);  off += h_b;
    int* cnt = (int*)(ws + off);
    off += align256((size_t)NNODES * cstride * sizeof(int));
    unsigned* edata = (unsigned*)(ws + off);          off += edata_b;

    hipMemsetAsync(cnt, 0, (size_t)NNODES * cstride * sizeof(int), stream);
    prep_kernel<<<GEMM_NB, 256, 0, stream>>>(rows, cols, vals, cnt, edata, ES, cstride, x, w, h);
    gather_kernel<<<(NNODES + RPB - 1) / RPB, 256, 0, stream>>>(h, cnt, edata, vals, bias, out, cstride, ES);
}

// Round 12
// 130.393 us; speedup vs baseline: 1.0216x; 1.0216x over previous
//
#include <hip/hip_runtime.h>
#include <math.h>

#define NNODES 50000
#define BB 4
#define FF 64
#define CAP 64   // max random-degree slots per row; Poisson(16) max over 50K nodes ~ 40

#define TROWS 64                             // gemm rows per block (4 waves x 16 rows, MFMA)
#define GEMM_NB ((BB * NNODES) / TROWS)      // 3125 blocks; 3125*256 == 800000 == ES
#define RPB 4                                // gather rows per block (1 per wave)

typedef _Float16 f16;
typedef __attribute__((ext_vector_type(4))) _Float16 f16x4;
typedef __attribute__((ext_vector_type(8))) _Float16 f16x8;
typedef __attribute__((ext_vector_type(4))) float f32x4;

// ---------------- helpers ----------------

__device__ inline unsigned short f2bf(float f) {            // round-to-nearest-even
    unsigned u = __float_as_uint(f);
    u += 0x7fffu + ((u >> 16) & 1u);
    return (unsigned short)(u >> 16);
}

__device__ inline void bf4fma(float v, uint2 hv, float& a0, float& a1, float& a2, float& a3) {
    a0 = fmaf(v, __uint_as_float(hv.x << 16),         a0);
    a1 = fmaf(v, __uint_as_float(hv.x & 0xffff0000u), a1);
    a2 = fmaf(v, __uint_as_float(hv.y << 16),         a2);
    a3 = fmaf(v, __uint_as_float(hv.y & 0xffff0000u), a3);
}

// ---------------- init: zero padded cnt + build W^T in f16 (8KB) ----------------

__global__ __launch_bounds__(256) void init_kernel(int* __restrict__ cnt, int n4,
                                                   const float* __restrict__ w,
                                                   f16* __restrict__ wt) {
    int i = blockIdx.x * 256 + threadIdx.x;
    if (i < n4) ((int4*)cnt)[i] = make_int4(0, 0, 0, 0);
    if (i < 1024) {                      // 64 f-rows x 16 k-quads
        int f = i >> 4, k0 = (i & 15) << 2;
        f16x4 v;
        v[0] = (f16)w[(k0 + 0) * 64 + f];
        v[1] = (f16)w[(k0 + 1) * 64 + f];
        v[2] = (f16)w[(k0 + 2) * 64 + f];
        v[3] = (f16)w[(k0 + 3) * 64 + f];
        *(f16x4*)(wt + f * 64 + k0) = v;
    }
}

// ---------------- fused prep: LDS-free MFMA gemm + scatter tail ----------------
// h[n][b][f](bf16) = x @ w via mfma_f32_16x16x32_f16 computed as C[f][m] =
// W^T x^T (operand swap): A = wt fragment (row=f=l&15 in tile, k=8*(l>>4)+j),
// B = x fragment (col=m=l&15, same k), C col=m, row(f)=4*(l>>4)+reg ->
// lane holds 4 CONTIGUOUS f values -> coalesced ushort4 h-store.
// x fragments come straight from global (quarter-waves tile the 128B half-row
// exactly -> coalesced); wt (8KB) is L1-hot. No LDS, no barrier.
// Each thread's ONE scatter edge is preloaded; atomic+store at the tail.

__global__ __launch_bounds__(256) void prep_kernel(const int* __restrict__ rows,
                                                   const int* __restrict__ cols,
                                                   const float* __restrict__ vals,
                                                   int* __restrict__ cnt,
                                                   unsigned* __restrict__ edata, int ES,
                                                   int cstride,
                                                   const float* __restrict__ x,
                                                   const f16* __restrict__ wt,
                                                   unsigned short* __restrict__ h) {
    int t = threadIdx.x;
    int wid = t >> 6, l = t & 63;

    // early edge load — in flight during the whole gemm
    int e = blockIdx.x * 256 + t;
    bool has_e = (e < ES);
    int r_e = 0, c_e = 0;
    float v_e = 0.f;
    if (has_e) { r_e = rows[e]; c_e = cols[e]; v_e = vals[e]; }

    long mcol = (long)blockIdx.x * TROWS + (wid << 4) + (l & 15);   // this lane's m (= b*N + n)
    int  kg   = (l >> 4) << 3;                                      // k-group base
    const float* xp = x + mcol * 64 + kg;
    float4 lo0, lo1, hi0, hi1;
    {
        const float4* p;
        p = (const float4*)(xp);
        lo0.x = __builtin_nontemporal_load(&p->x); lo0.y = __builtin_nontemporal_load(&p->y);
        lo0.z = __builtin_nontemporal_load(&p->z); lo0.w = __builtin_nontemporal_load(&p->w);
        p = (const float4*)(xp + 4);
        lo1.x = __builtin_nontemporal_load(&p->x); lo1.y = __builtin_nontemporal_load(&p->y);
        lo1.z = __builtin_nontemporal_load(&p->z); lo1.w = __builtin_nontemporal_load(&p->w);
        p = (const float4*)(xp + 32);
        hi0.x = __builtin_nontemporal_load(&p->x); hi0.y = __builtin_nontemporal_load(&p->y);
        hi0.z = __builtin_nontemporal_load(&p->z); hi0.w = __builtin_nontemporal_load(&p->w);
        p = (const float4*)(xp + 36);
        hi1.x = __builtin_nontemporal_load(&p->x); hi1.y = __builtin_nontemporal_load(&p->y);
        hi1.z = __builtin_nontemporal_load(&p->z); hi1.w = __builtin_nontemporal_load(&p->w);
    }
    f16x8 aLo, aHi;
    aLo[0] = (f16)lo0.x; aLo[1] = (f16)lo0.y; aLo[2] = (f16)lo0.z; aLo[3] = (f16)lo0.w;
    aLo[4] = (f16)lo1.x; aLo[5] = (f16)lo1.y; aLo[6] = (f16)lo1.z; aLo[7] = (f16)lo1.w;
    aHi[0] = (f16)hi0.x; aHi[1] = (f16)hi0.y; aHi[2] = (f16)hi0.z; aHi[3] = (f16)hi0.w;
    aHi[4] = (f16)hi1.x; aHi[5] = (f16)hi1.y; aHi[6] = (f16)hi1.z; aHi[7] = (f16)hi1.w;

    f32x4 acc[4] = {{0.f,0.f,0.f,0.f},{0.f,0.f,0.f,0.f},{0.f,0.f,0.f,0.f},{0.f,0.f,0.f,0.f}};
    #pragma unroll
    for (int c = 0; c < 4; ++c) {                        // f-tiles of 16
        f16x8 bLo = *(const f16x8*)(wt + (c * 16 + (l & 15)) * 64 + kg);
        f16x8 bHi = *(const f16x8*)(wt + (c * 16 + (l & 15)) * 64 + 32 + kg);
        acc[c] = __builtin_amdgcn_mfma_f32_16x16x32_f16(bLo, aLo, acc[c], 0, 0, 0);
        acc[c] = __builtin_amdgcn_mfma_f32_16x16x32_f16(bHi, aHi, acc[c], 0, 0, 0);
    }

    // store h bf16 into [n][b][f]: lane's 4 regs = 4 contiguous f -> ushort4
    int b = (int)(mcol / NNODES);
    int n = (int)(mcol - (long)b * NNODES);
    unsigned short* hp = h + ((size_t)n * BB + b) * 64 + ((l >> 4) << 2);
    #pragma unroll
    for (int c = 0; c < 4; ++c) {
        ushort4 o;
        o.x = f2bf(acc[c][0]); o.y = f2bf(acc[c][1]);
        o.z = f2bf(acc[c][2]); o.w = f2bf(acc[c][3]);
        *(ushort4*)(hp + c * 16) = o;
    }

    // scatter tail
    if (has_e) {
        int pos = atomicAdd(&cnt[(size_t)r_e * cstride], 1);
        if (pos < CAP) {
            unsigned p = ((unsigned)f2bf(v_e) << 16) | (unsigned)c_e;
            edata[(size_t)r_e * CAP + pos] = p;
        }
    }
}

// ---------------- out[b,r,:] = ELU(bias + val_self*h[r] + sum_e val*h[col]) ----------------
// one wave per row; lane: b = lane>>4, feature quad fq = lane&15.
// Packed edge list loaded ONCE (masked, coalesced, non-temporal); per iteration
// (col,val) decode from one __shfl broadcast. Inner loop padded to a multiple
// of 8 with zero-val edges so there is NO serial tail.

__global__ __launch_bounds__(256) void gather_kernel(const unsigned short* __restrict__ h,
                                                     const int* __restrict__ cnt,
                                                     const unsigned* __restrict__ edata,
                                                     const float* __restrict__ vals,
                                                     const float* __restrict__ bias,
                                                     float* __restrict__ out,
                                                     int cstride, int ES) {
    int wave = threadIdx.x >> 6;
    int lane = threadIdx.x & 63;
    int r = blockIdx.x * RPB + wave;
    if (r >= NNODES) return;
    int deg = cnt[(size_t)r * cstride];
    if (deg > CAP) deg = CAP;
    int b  = lane >> 4;
    int fq = lane & 15;
    const unsigned short* hb = h + b * 64 + fq * 4;   // lane's base within a node's 256 elems
    unsigned my_p = 0u;
    if (lane < deg) {                                  // masked + NT: stream, don't cache
        const unsigned* ep = &edata[(size_t)r * CAP + lane];
        my_p = __builtin_nontemporal_load(ep);
    }
    // self-loop issued early (independent load in flight during the edge loop)
    float vs = vals[ES + r];
    uint2 hs = *(const uint2*)(hb + (size_t)r * 256);
    float4 b4 = ((const float4*)bias)[fq];

    float a0 = 0.f, a1 = 0.f, a2 = 0.f, a3 = 0.f;
    int dg8 = (deg + 7) & ~7;                          // <= 64
    for (int k = 0; k < dg8; k += 8) {
        unsigned p0 = __shfl(my_p, k,     64), p1 = __shfl(my_p, k + 1, 64);
        unsigned p2 = __shfl(my_p, k + 2, 64), p3 = __shfl(my_p, k + 3, 64);
        unsigned p4 = __shfl(my_p, k + 4, 64), p5 = __shfl(my_p, k + 5, 64);
        unsigned p6 = __shfl(my_p, k + 6, 64), p7 = __shfl(my_p, k + 7, 64);
        uint2 h0 = *(const uint2*)(hb + (size_t)(p0 & 0xFFFFu) * 256);
        uint2 h1 = *(const uint2*)(hb + (size_t)(p1 & 0xFFFFu) * 256);
        uint2 h2 = *(const uint2*)(hb + (size_t)(p2 & 0xFFFFu) * 256);
        uint2 h3 = *(const uint2*)(hb + (size_t)(p3 & 0xFFFFu) * 256);
        uint2 h4 = *(const uint2*)(hb + (size_t)(p4 & 0xFFFFu) * 256);
        uint2 h5 = *(const uint2*)(hb + (size_t)(p5 & 0xFFFFu) * 256);
        uint2 h6 = *(const uint2*)(hb + (size_t)(p6 & 0xFFFFu) * 256);
        uint2 h7 = *(const uint2*)(hb + (size_t)(p7 & 0xFFFFu) * 256);
        bf4fma(__uint_as_float(p0 & 0xFFFF0000u), h0, a0, a1, a2, a3);
        bf4fma(__uint_as_float(p1 & 0xFFFF0000u), h1, a0, a1, a2, a3);
        bf4fma(__uint_as_float(p2 & 0xFFFF0000u), h2, a0, a1, a2, a3);
        bf4fma(__uint_as_float(p3 & 0xFFFF0000u), h3, a0, a1, a2, a3);
        bf4fma(__uint_as_float(p4 & 0xFFFF0000u), h4, a0, a1, a2, a3);
        bf4fma(__uint_as_float(p5 & 0xFFFF0000u), h5, a0, a1, a2, a3);
        bf4fma(__uint_as_float(p6 & 0xFFFF0000u), h6, a0, a1, a2, a3);
        bf4fma(__uint_as_float(p7 & 0xFFFF0000u), h7, a0, a1, a2, a3);
    }
    // self-loop contribution (reference appends self-loops last: val = vals[ES+r])
    bf4fma(vs, hs, a0, a1, a2, a3);
    a0 += b4.x; a1 += b4.y; a2 += b4.z; a3 += b4.w;
    a0 = a0 > 0.f ? a0 : expm1f(a0);
    a1 = a1 > 0.f ? a1 : expm1f(a1);
    a2 = a2 > 0.f ? a2 : expm1f(a2);
    a3 = a3 > 0.f ? a3 : expm1f(a3);
    float4 o = make_float4(a0, a1, a2, a3);
    *(float4*)(out + ((size_t)b * NNODES + r) * 64 + fq * 4) = o;   // plain store (harness-validated buffer)
}

// ---------------- launch ----------------

static inline size_t align256(size_t x) { return (x + 255) & ~(size_t)255; }

extern "C" void kernel_launch(void* const* d_in, const int* in_sizes, int n_in,
                              void* d_out, int out_size, void* d_ws, size_t ws_size,
                              hipStream_t stream) {
    const float* x    = (const float*)d_in[0];
    const float* vals = (const float*)d_in[1];
    const float* w    = (const float*)d_in[2];
    const float* bias = (const float*)d_in[3];
    const int*   rows = (const int*)d_in[4];
    const int*   cols = (const int*)d_in[5];
    float* out = (float*)d_out;
    const int E  = in_sizes[1];
    const int ES = E - NNODES;                       // random edges (self-loops are the last N)

    // cnt padded to one counter per 64B line if workspace allows; fallback stride 1.
    size_t h_b     = align256((size_t)BB * NNODES * FF * sizeof(unsigned short)); // 25.6 MB
    size_t edata_b = align256((size_t)NNODES * CAP * sizeof(unsigned));           // 12.8 MB
    size_t wt_b    = align256((size_t)64 * 64 * sizeof(f16));                     // 8 KB
    int cstride = 16;
    if (h_b + edata_b + wt_b + align256((size_t)NNODES * 16 * sizeof(int)) > ws_size) cstride = 1;

    char* ws = (char*)d_ws;
    size_t off = 0;
    unsigned short* h = (unsigned short*)(ws + off);  off += h_b;
    int* cnt = (int*)(ws + off);
    off += align256((size_t)NNODES * cstride * sizeof(int));
    unsigned* edata = (unsigned*)(ws + off);          off += edata_b;
    f16* wt = (f16*)(ws + off);                       off += wt_b;

    int n4 = (NNODES * cstride) / 4;                  // int4 chunks of cnt

    init_kernel<<<(n4 + 255) / 256, 256, 0, stream>>>(cnt, n4, w, wt);
    prep_kernel<<<GEMM_NB, 256, 0, stream>>>(rows, cols, vals, cnt, edata, ES, cstride, x, wt, h);
    gather_kernel<<<(NNODES + RPB - 1) / RPB, 256, 0, stream>>>(h, cnt, edata, vals, bias, out, cstride, ES);
}

// Round 13
// 125.201 us; speedup vs baseline: 1.0640x; 1.0415x over previous
//
#include <hip/hip_runtime.h>
#include <math.h>

#define NNODES 50000
#define BB 4
#define FF 64
#define CAP 64   // max random-degree slots per row; Poisson(16) max over 50K nodes ~ 40

#define TROWS 64                             // gemm rows per block (4 waves x 16 cols, MFMA)
#define GEMM_NB ((BB * NNODES) / TROWS)      // 3125 gemm blocks
#define SC_EPB 512                           // edges per scatter block (256 thr x 2)
#define SC_NB 1563                           // scatter blocks: 1563*512 >= 800000
#define RPB 4                                // gather rows per block (1 per wave)

typedef _Float16 f16;
typedef __attribute__((ext_vector_type(4))) _Float16 f16x4;
typedef __attribute__((ext_vector_type(8))) _Float16 f16x8;
typedef __attribute__((ext_vector_type(4))) float f32x4;

// ---------------- helpers ----------------

__device__ inline unsigned short f2bf(float f) {            // round-to-nearest-even
    unsigned u = __float_as_uint(f);
    u += 0x7fffu + ((u >> 16) & 1u);
    return (unsigned short)(u >> 16);
}

__device__ inline void bf4fma(float v, uint2 hv, float& a0, float& a1, float& a2, float& a3) {
    a0 = fmaf(v, __uint_as_float(hv.x << 16),         a0);
    a1 = fmaf(v, __uint_as_float(hv.x & 0xffff0000u), a1);
    a2 = fmaf(v, __uint_as_float(hv.y << 16),         a2);
    a3 = fmaf(v, __uint_as_float(hv.y & 0xffff0000u), a3);
}

// ---------------- init: zero padded cnt + build W^T in f16 (8KB) ----------------

__global__ __launch_bounds__(256) void init_kernel(int* __restrict__ cnt, int n4,
                                                   const float* __restrict__ w,
                                                   f16* __restrict__ wt) {
    int i = blockIdx.x * 256 + threadIdx.x;
    if (i < n4) ((int4*)cnt)[i] = make_int4(0, 0, 0, 0);
    if (i < 1024) {                      // 64 f-rows x 16 k-quads
        int f = i >> 4, k0 = (i & 15) << 2;
        f16x4 v;
        v[0] = (f16)w[(k0 + 0) * 64 + f];
        v[1] = (f16)w[(k0 + 1) * 64 + f];
        v[2] = (f16)w[(k0 + 2) * 64 + f];
        v[3] = (f16)w[(k0 + 3) * 64 + f];
        *(f16x4*)(wt + f * 64 + k0) = v;
    }
}

// ---------------- fused prep: interleaved block roles ----------------
// Every 3rd block (bid%3==2) is a SCATTER block (512 edges, 2 independent
// atomic+store chains per thread); the rest run the LDS-free MFMA gemm.
// Dispatch-order interleaving staggers the atomic bursts across the whole
// gemm streaming window -> latency hides under 77MB of gemm r+w traffic.
// (R5's version of this failed because 34KB LDS was charged to scatter
// blocks; this gemm uses NO LDS.)
//
// gemm: h[n][b][f](bf16) = x @ w via mfma_f32_16x16x32_f16 as C[f][m] =
// W^T x^T (operand swap): lane's 4 C-regs = 4 contiguous f -> ushort4 store.
// x fragments straight from global (coalesced); wt (8KB) L1-hot.

__global__ __launch_bounds__(256) void prep_kernel(const int* __restrict__ rows,
                                                   const int* __restrict__ cols,
                                                   const float* __restrict__ vals,
                                                   int* __restrict__ cnt,
                                                   unsigned* __restrict__ edata, int ES,
                                                   int cstride,
                                                   const float* __restrict__ x,
                                                   const f16* __restrict__ wt,
                                                   unsigned short* __restrict__ h) {
    int t = threadIdx.x;
    int bid = blockIdx.x;
    int tri = bid / 3, rem = bid - tri * 3;

    if (rem == 2) {
        // ---- scatter block: 512 edges, 2 per thread (independent chains) ----
        int ebase = tri * SC_EPB;
        int e0 = ebase + t, e1 = ebase + 256 + t;
        bool h0 = (e0 < ES), h1 = (e1 < ES);
        int r0 = 0, c0 = 0, r1 = 0, c1 = 0;
        float v0 = 0.f, v1 = 0.f;
        if (h0) { r0 = rows[e0]; c0 = cols[e0]; v0 = vals[e0]; }
        if (h1) { r1 = rows[e1]; c1 = cols[e1]; v1 = vals[e1]; }
        if (h0) {
            int pos = atomicAdd(&cnt[(size_t)r0 * cstride], 1);
            if (pos < CAP)
                edata[(size_t)r0 * CAP + pos] = ((unsigned)f2bf(v0) << 16) | (unsigned)c0;
        }
        if (h1) {
            int pos = atomicAdd(&cnt[(size_t)r1 * cstride], 1);
            if (pos < CAP)
                edata[(size_t)r1 * CAP + pos] = ((unsigned)f2bf(v1) << 16) | (unsigned)c1;
        }
        return;
    }

    // ---- gemm block ----
    int g = tri * 2 + rem;
    if (g >= GEMM_NB) return;
    int wid = t >> 6, l = t & 63;
    long mcol = (long)g * TROWS + (wid << 4) + (l & 15);   // this lane's m (= b*N + n)
    int  kg   = (l >> 4) << 3;                             // k-group base
    const float* xp = x + mcol * 64 + kg;
    float4 lo0, lo1, hi0, hi1;
    {
        const float4* p;
        p = (const float4*)(xp);
        lo0.x = __builtin_nontemporal_load(&p->x); lo0.y = __builtin_nontemporal_load(&p->y);
        lo0.z = __builtin_nontemporal_load(&p->z); lo0.w = __builtin_nontemporal_load(&p->w);
        p = (const float4*)(xp + 4);
        lo1.x = __builtin_nontemporal_load(&p->x); lo1.y = __builtin_nontemporal_load(&p->y);
        lo1.z = __builtin_nontemporal_load(&p->z); lo1.w = __builtin_nontemporal_load(&p->w);
        p = (const float4*)(xp + 32);
        hi0.x = __builtin_nontemporal_load(&p->x); hi0.y = __builtin_nontemporal_load(&p->y);
        hi0.z = __builtin_nontemporal_load(&p->z); hi0.w = __builtin_nontemporal_load(&p->w);
        p = (const float4*)(xp + 36);
        hi1.x = __builtin_nontemporal_load(&p->x); hi1.y = __builtin_nontemporal_load(&p->y);
        hi1.z = __builtin_nontemporal_load(&p->z); hi1.w = __builtin_nontemporal_load(&p->w);
    }
    f16x8 aLo, aHi;
    aLo[0] = (f16)lo0.x; aLo[1] = (f16)lo0.y; aLo[2] = (f16)lo0.z; aLo[3] = (f16)lo0.w;
    aLo[4] = (f16)lo1.x; aLo[5] = (f16)lo1.y; aLo[6] = (f16)lo1.z; aLo[7] = (f16)lo1.w;
    aHi[0] = (f16)hi0.x; aHi[1] = (f16)hi0.y; aHi[2] = (f16)hi0.z; aHi[3] = (f16)hi0.w;
    aHi[4] = (f16)hi1.x; aHi[5] = (f16)hi1.y; aHi[6] = (f16)hi1.z; aHi[7] = (f16)hi1.w;

    f32x4 acc[4] = {{0.f,0.f,0.f,0.f},{0.f,0.f,0.f,0.f},{0.f,0.f,0.f,0.f},{0.f,0.f,0.f,0.f}};
    #pragma unroll
    for (int c = 0; c < 4; ++c) {                        // f-tiles of 16
        f16x8 bLo = *(const f16x8*)(wt + (c * 16 + (l & 15)) * 64 + kg);
        f16x8 bHi = *(const f16x8*)(wt + (c * 16 + (l & 15)) * 64 + 32 + kg);
        acc[c] = __builtin_amdgcn_mfma_f32_16x16x32_f16(bLo, aLo, acc[c], 0, 0, 0);
        acc[c] = __builtin_amdgcn_mfma_f32_16x16x32_f16(bHi, aHi, acc[c], 0, 0, 0);
    }

    // store h bf16 into [n][b][f]: lane's 4 regs = 4 contiguous f -> ushort4
    int b = (int)(mcol / NNODES);
    int n = (int)(mcol - (long)b * NNODES);
    unsigned short* hp = h + ((size_t)n * BB + b) * 64 + ((l >> 4) << 2);
    #pragma unroll
    for (int c = 0; c < 4; ++c) {
        ushort4 o;
        o.x = f2bf(acc[c][0]); o.y = f2bf(acc[c][1]);
        o.z = f2bf(acc[c][2]); o.w = f2bf(acc[c][3]);
        *(ushort4*)(hp + c * 16) = o;
    }
}

// ---------------- out[b,r,:] = ELU(bias + val_self*h[r] + sum_e val*h[col]) ----------------
// one wave per row; lane: b = lane>>4, feature quad fq = lane&15.
// Packed edge list loaded ONCE (masked, coalesced, non-temporal); per iteration
// (col,val) decode from one __shfl broadcast. Inner loop padded to a multiple
// of 8 with zero-val edges so there is NO serial tail.

__global__ __launch_bounds__(256) void gather_kernel(const unsigned short* __restrict__ h,
                                                     const int* __restrict__ cnt,
                                                     const unsigned* __restrict__ edata,
                                                     const float* __restrict__ vals,
                                                     const float* __restrict__ bias,
                                                     float* __restrict__ out,
                                                     int cstride, int ES) {
    int wave = threadIdx.x >> 6;
    int lane = threadIdx.x & 63;
    int r = blockIdx.x * RPB + wave;
    if (r >= NNODES) return;
    int deg = cnt[(size_t)r * cstride];
    if (deg > CAP) deg = CAP;
    int b  = lane >> 4;
    int fq = lane & 15;
    const unsigned short* hb = h + b * 64 + fq * 4;   // lane's base within a node's 256 elems
    unsigned my_p = 0u;
    if (lane < deg) {                                  // masked + NT: stream, don't cache
        const unsigned* ep = &edata[(size_t)r * CAP + lane];
        my_p = __builtin_nontemporal_load(ep);
    }
    // self-loop issued early (independent load in flight during the edge loop)
    float vs = vals[ES + r];
    uint2 hs = *(const uint2*)(hb + (size_t)r * 256);
    float4 b4 = ((const float4*)bias)[fq];

    float a0 = 0.f, a1 = 0.f, a2 = 0.f, a3 = 0.f;
    int dg8 = (deg + 7) & ~7;                          // <= 64
    for (int k = 0; k < dg8; k += 8) {
        unsigned p0 = __shfl(my_p, k,     64), p1 = __shfl(my_p, k + 1, 64);
        unsigned p2 = __shfl(my_p, k + 2, 64), p3 = __shfl(my_p, k + 3, 64);
        unsigned p4 = __shfl(my_p, k + 4, 64), p5 = __shfl(my_p, k + 5, 64);
        unsigned p6 = __shfl(my_p, k + 6, 64), p7 = __shfl(my_p, k + 7, 64);
        uint2 h0 = *(const uint2*)(hb + (size_t)(p0 & 0xFFFFu) * 256);
        uint2 h1 = *(const uint2*)(hb + (size_t)(p1 & 0xFFFFu) * 256);
        uint2 h2 = *(const uint2*)(hb + (size_t)(p2 & 0xFFFFu) * 256);
        uint2 h3 = *(const uint2*)(hb + (size_t)(p3 & 0xFFFFu) * 256);
        uint2 h4 = *(const uint2*)(hb + (size_t)(p4 & 0xFFFFu) * 256);
        uint2 h5 = *(const uint2*)(hb + (size_t)(p5 & 0xFFFFu) * 256);
        uint2 h6 = *(const uint2*)(hb + (size_t)(p6 & 0xFFFFu) * 256);
        uint2 h7 = *(const uint2*)(hb + (size_t)(p7 & 0xFFFFu) * 256);
        bf4fma(__uint_as_float(p0 & 0xFFFF0000u), h0, a0, a1, a2, a3);
        bf4fma(__uint_as_float(p1 & 0xFFFF0000u), h1, a0, a1, a2, a3);
        bf4fma(__uint_as_float(p2 & 0xFFFF0000u), h2, a0, a1, a2, a3);
        bf4fma(__uint_as_float(p3 & 0xFFFF0000u), h3, a0, a1, a2, a3);
        bf4fma(__uint_as_float(p4 & 0xFFFF0000u), h4, a0, a1, a2, a3);
        bf4fma(__uint_as_float(p5 & 0xFFFF0000u), h5, a0, a1, a2, a3);
        bf4fma(__uint_as_float(p6 & 0xFFFF0000u), h6, a0, a1, a2, a3);
        bf4fma(__uint_as_float(p7 & 0xFFFF0000u), h7, a0, a1, a2, a3);
    }
    // self-loop contribution (reference appends self-loops last: val = vals[ES+r])
    bf4fma(vs, hs, a0, a1, a2, a3);
    a0 += b4.x; a1 += b4.y; a2 += b4.z; a3 += b4.w;
    a0 = a0 > 0.f ? a0 : expm1f(a0);
    a1 = a1 > 0.f ? a1 : expm1f(a1);
    a2 = a2 > 0.f ? a2 : expm1f(a2);
    a3 = a3 > 0.f ? a3 : expm1f(a3);
    float4 o = make_float4(a0, a1, a2, a3);
    *(float4*)(out + ((size_t)b * NNODES + r) * 64 + fq * 4) = o;   // plain store (harness-validated buffer)
}

// ---------------- launch ----------------

static inline size_t align256(size_t x) { return (x + 255) & ~(size_t)255; }

extern "C" void kernel_launch(void* const* d_in, const int* in_sizes, int n_in,
                              void* d_out, int out_size, void* d_ws, size_t ws_size,
                              hipStream_t stream) {
    const float* x    = (const float*)d_in[0];
    const float* vals = (const float*)d_in[1];
    const float* w    = (const float*)d_in[2];
    const float* bias = (const float*)d_in[3];
    const int*   rows = (const int*)d_in[4];
    const int*   cols = (const int*)d_in[5];
    float* out = (float*)d_out;
    const int E  = in_sizes[1];
    const int ES = E - NNODES;                       // random edges (self-loops are the last N)

    // cnt padded to one counter per 64B line if workspace allows; fallback stride 1.
    size_t h_b     = align256((size_t)BB * NNODES * FF * sizeof(unsigned short)); // 25.6 MB
    size_t edata_b = align256((size_t)NNODES * CAP * sizeof(unsigned));           // 12.8 MB
    size_t wt_b    = align256((size_t)64 * 64 * sizeof(f16));                     // 8 KB
    int cstride = 16;
    if (h_b + edata_b + wt_b + align256((size_t)NNODES * 16 * sizeof(int)) > ws_size) cstride = 1;

    char* ws = (char*)d_ws;
    size_t off = 0;
    unsigned short* h = (unsigned short*)(ws + off);  off += h_b;
    int* cnt = (int*)(ws + off);
    off += align256((size_t)NNODES * cstride * sizeof(int));
    unsigned* edata = (unsigned*)(ws + off);          off += edata_b;
    f16* wt = (f16*)(ws + off);                       off += wt_b;

    int n4 = (NNODES * cstride) / 4;                  // int4 chunks of cnt
    int NB = 3 * SC_NB;                               // 4689: 2 gemm : 1 scatter interleave

    init_kernel<<<(n4 + 255) / 256, 256, 0, stream>>>(cnt, n4, w, wt);
    prep_kernel<<<NB, 256, 0, stream>>>(rows, cols, vals, cnt, edata, ES, cstride, x, wt, h);
    gather_kernel<<<(NNODES + RPB - 1) / RPB, 256, 0, stream>>>(h, cnt, edata, vals, bias, out, cstride, ES);
}

// Round 14
// 111.364 us; speedup vs baseline: 1.1962x; 1.1243x over previous
//
#include <hip/hip_runtime.h>
#include <math.h>

#define NNODES 50000
#define BB 4
#define FF 64
#define CAP 64   // max random-degree slots per row; Poisson(16) max over 50K nodes ~ 40

#define TROWS 32                             // gemm rows per block (proven R10 structure)
#define GEMM_NB ((BB * NNODES) / TROWS)      // 6250 blocks
#define RPB 4                                // gather rows per block (1 per wave)

// ---------------- helpers ----------------

__device__ inline unsigned short f2bf(float f) {            // round-to-nearest-even
    unsigned u = __float_as_uint(f);
    u += 0x7fffu + ((u >> 16) & 1u);
    return (unsigned short)(u >> 16);
}

__device__ inline void bf4fma(float v, uint2 hv, float& a0, float& a1, float& a2, float& a3) {
    a0 = fmaf(v, __uint_as_float(hv.x << 16),         a0);
    a1 = fmaf(v, __uint_as_float(hv.x & 0xffff0000u), a1);
    a2 = fmaf(v, __uint_as_float(hv.y << 16),         a2);
    a3 = fmaf(v, __uint_as_float(hv.y & 0xffff0000u), a3);
}

// ---------------- fused prep: VALU gemm first, scatter as the kernel tail ----------------
// (Proven R10 structure, ~45us: 6250 blocks whose staggered generations give the
// scatter atomics long-lived co-resident compute to hide under. MFMA/interleaved
// variants R11-R13 all exposed the scatter at ~60us.)
// Edge record packed to u32: (bf16(val) << 16) | col   (col < 50000 < 2^16).

__global__ __launch_bounds__(256) void prep_kernel(const int* __restrict__ rows,
                                                   const int* __restrict__ cols,
                                                   const float* __restrict__ vals,
                                                   int* __restrict__ cnt,
                                                   unsigned* __restrict__ edata, int ES, int EPB,
                                                   int cstride,
                                                   const float* __restrict__ x,
                                                   const float* __restrict__ w,
                                                   unsigned short* __restrict__ h) {
    __shared__ float xs[TROWS][68];
    __shared__ float wsh[64][68];
    int t = threadIdx.x;
    long rowBase = (long)blockIdx.x * TROWS;

    // stage x/w tiles to LDS
    #pragma unroll
    for (int i = 0; i < 2; ++i) {
        int s = t + i * 256;          // 512 float4 slots: 32 rows x 16
        int r = s >> 4, c4 = s & 15;
        const float4* xp = (const float4*)(x + (rowBase + r) * 64 + c4 * 4);
        float4 xv;
        xv.x = __builtin_nontemporal_load(&xp->x);
        xv.y = __builtin_nontemporal_load(&xp->y);
        xv.z = __builtin_nontemporal_load(&xp->z);
        xv.w = __builtin_nontemporal_load(&xp->w);
        *(float4*)&xs[r][c4 * 4] = xv;
    }
    #pragma unroll
    for (int i = 0; i < 4; ++i) {
        int s = t + i * 256;          // 1024 float4 slots: 64 rows x 16
        int r = s >> 4, c4 = s & 15;
        *(float4*)&wsh[r][c4 * 4] = *(const float4*)(w + r * 64 + c4 * 4);
    }
    __syncthreads();

    // gemm: h[n][b][f] (bf16) = x[b][n][:] @ w
    int ty = t >> 4, tx = t & 15;
    int r0 = ty * 2, c0 = tx * 4;     // thread tile: 2 rows x 4 cols
    float acc[2][4] = {};
    #pragma unroll
    for (int f4 = 0; f4 < 16; ++f4) {
        float a[2][4], b[4][4];
        #pragma unroll
        for (int i = 0; i < 2; ++i)
            #pragma unroll
            for (int k = 0; k < 4; ++k) a[i][k] = xs[r0 + i][f4 * 4 + k];
        #pragma unroll
        for (int k = 0; k < 4; ++k)
            #pragma unroll
            for (int j = 0; j < 4; ++j) b[k][j] = wsh[f4 * 4 + k][c0 + j];
        #pragma unroll
        for (int i = 0; i < 2; ++i)
            #pragma unroll
            for (int k = 0; k < 4; ++k)
                #pragma unroll
                for (int j = 0; j < 4; ++j) acc[i][j] = fmaf(a[i][k], b[k][j], acc[i][j]);
    }
    #pragma unroll
    for (int i = 0; i < 2; ++i) {
        long m = rowBase + r0 + i;          // m = b*N + n
        int  b = (int)(m / NNODES);
        int  n = (int)(m - (long)b * NNODES);
        ushort4 o;
        o.x = f2bf(acc[i][0]); o.y = f2bf(acc[i][1]);
        o.z = f2bf(acc[i][2]); o.w = f2bf(acc[i][3]);
        *(ushort4*)(h + ((size_t)n * BB + b) * 64 + c0) = o;
    }

    // scatter tail: this block's chunk of the E-N random edges (self-loops excluded)
    int e = blockIdx.x * EPB + t;
    if (t < EPB && e < ES) {
        int r = rows[e];
        int pos = atomicAdd(&cnt[(size_t)r * cstride], 1);
        if (pos < CAP) {
            unsigned p = ((unsigned)f2bf(vals[e]) << 16) | (unsigned)cols[e];
            edata[(size_t)r * CAP + pos] = p;
        }
    }
}

// ---------------- out[b,r,:] = ELU(bias + val_self*h[r] + sum_e val*h[col]) ----------------
// one wave per row; lane: b = lane>>4, feature quad fq = lane&15.
// Packed edge list loaded ONCE (masked, coalesced, non-temporal). Per edge the
// wave-uniform record is broadcast via v_readlane (NOT __shfl/ds_bpermute):
// decode and base-address computation live on the SCALAR pipe, so the VALU
// per edge is just 4 fma. Loop padded to a multiple of 8 with zero-val edges
// (p=0 -> col 0, val +0) so there is NO serial tail.

__global__ __launch_bounds__(256) void gather_kernel(const unsigned short* __restrict__ h,
                                                     const int* __restrict__ cnt,
                                                     const unsigned* __restrict__ edata,
                                                     const float* __restrict__ vals,
                                                     const float* __restrict__ bias,
                                                     float* __restrict__ out,
                                                     int cstride, int ES) {
    int wave = threadIdx.x >> 6;
    int lane = threadIdx.x & 63;
    int r = blockIdx.x * RPB + wave;
    if (r >= NNODES) return;
    int deg = cnt[(size_t)r * cstride];
    if (deg > CAP) deg = CAP;
    int b  = lane >> 4;
    int fq = lane & 15;
    const unsigned short* hb = h + b * 64 + fq * 4;   // lane's base within a node's 256 elems
    unsigned my_p = 0u;
    if (lane < deg) {                                  // masked + NT: stream, don't cache
        const unsigned* ep = &edata[(size_t)r * CAP + lane];
        my_p = __builtin_nontemporal_load(ep);
    }
    // self-loop issued early (independent load in flight during the edge loop)
    float vs = vals[ES + r];
    uint2 hs = *(const uint2*)(hb + (size_t)r * 256);
    float4 b4 = ((const float4*)bias)[fq];

    float a0 = 0.f, a1 = 0.f, a2 = 0.f, a3 = 0.f;
    int dg8 = (deg + 7) & ~7;                          // <= 64
    for (int k = 0; k < dg8; k += 8) {
        unsigned p0 = (unsigned)__builtin_amdgcn_readlane((int)my_p, k);
        unsigned p1 = (unsigned)__builtin_amdgcn_readlane((int)my_p, k + 1);
        unsigned p2 = (unsigned)__builtin_amdgcn_readlane((int)my_p, k + 2);
        unsigned p3 = (unsigned)__builtin_amdgcn_readlane((int)my_p, k + 3);
        unsigned p4 = (unsigned)__builtin_amdgcn_readlane((int)my_p, k + 4);
        unsigned p5 = (unsigned)__builtin_amdgcn_readlane((int)my_p, k + 5);
        unsigned p6 = (unsigned)__builtin_amdgcn_readlane((int)my_p, k + 6);
        unsigned p7 = (unsigned)__builtin_amdgcn_readlane((int)my_p, k + 7);
        uint2 h0 = *(const uint2*)(hb + (size_t)(p0 & 0xFFFFu) * 256);
        uint2 h1 = *(const uint2*)(hb + (size_t)(p1 & 0xFFFFu) * 256);
        uint2 h2 = *(const uint2*)(hb + (size_t)(p2 & 0xFFFFu) * 256);
        uint2 h3 = *(const uint2*)(hb + (size_t)(p3 & 0xFFFFu) * 256);
        uint2 h4 = *(const uint2*)(hb + (size_t)(p4 & 0xFFFFu) * 256);
        uint2 h5 = *(const uint2*)(hb + (size_t)(p5 & 0xFFFFu) * 256);
        uint2 h6 = *(const uint2*)(hb + (size_t)(p6 & 0xFFFFu) * 256);
        uint2 h7 = *(const uint2*)(hb + (size_t)(p7 & 0xFFFFu) * 256);
        bf4fma(__uint_as_float(p0 & 0xFFFF0000u), h0, a0, a1, a2, a3);
        bf4fma(__uint_as_float(p1 & 0xFFFF0000u), h1, a0, a1, a2, a3);
        bf4fma(__uint_as_float(p2 & 0xFFFF0000u), h2, a0, a1, a2, a3);
        bf4fma(__uint_as_float(p3 & 0xFFFF0000u), h3, a0, a1, a2, a3);
        bf4fma(__uint_as_float(p4 & 0xFFFF0000u), h4, a0, a1, a2, a3);
        bf4fma(__uint_as_float(p5 & 0xFFFF0000u), h5, a0, a1, a2, a3);
        bf4fma(__uint_as_float(p6 & 0xFFFF0000u), h6, a0, a1, a2, a3);
        bf4fma(__uint_as_float(p7 & 0xFFFF0000u), h7, a0, a1, a2, a3);
    }
    // self-loop contribution (reference appends self-loops last: val = vals[ES+r])
    bf4fma(vs, hs, a0, a1, a2, a3);
    a0 += b4.x; a1 += b4.y; a2 += b4.z; a3 += b4.w;
    a0 = a0 > 0.f ? a0 : expm1f(a0);
    a1 = a1 > 0.f ? a1 : expm1f(a1);
    a2 = a2 > 0.f ? a2 : expm1f(a2);
    a3 = a3 > 0.f ? a3 : expm1f(a3);
    float4 o = make_float4(a0, a1, a2, a3);
    *(float4*)(out + ((size_t)b * NNODES + r) * 64 + fq * 4) = o;   // plain store (harness-validated buffer)
}

// ---------------- launch ----------------

static inline size_t align256(size_t x) { return (x + 255) & ~(size_t)255; }

extern "C" void kernel_launch(void* const* d_in, const int* in_sizes, int n_in,
                              void* d_out, int out_size, void* d_ws, size_t ws_size,
                              hipStream_t stream) {
    const float* x    = (const float*)d_in[0];
    const float* vals = (const float*)d_in[1];
    const float* w    = (const float*)d_in[2];
    const float* bias = (const float*)d_in[3];
    const int*   rows = (const int*)d_in[4];
    const int*   cols = (const int*)d_in[5];
    float* out = (float*)d_out;
    const int E  = in_sizes[1];
    const int ES = E - NNODES;                       // random edges (self-loops are the last N)

    // cnt padded to one counter per 64B line if workspace allows; fallback stride 1.
    size_t h_b     = align256((size_t)BB * NNODES * FF * sizeof(unsigned short)); // 25.6 MB
    size_t edata_b = align256((size_t)NNODES * CAP * sizeof(unsigned));           // 12.8 MB
    int cstride = 16;
    if (h_b + edata_b + align256((size_t)NNODES * 16 * sizeof(int)) > ws_size) cstride = 1;

    char* ws = (char*)d_ws;
    size_t off = 0;
    unsigned short* h = (unsigned short*)(ws + off);  off += h_b;
    int* cnt = (int*)(ws + off);
    off += align256((size_t)NNODES * cstride * sizeof(int));
    unsigned* edata = (unsigned*)(ws + off);          off += edata_b;

    int EPB = (ES + GEMM_NB - 1) / GEMM_NB;           // 128 edges per block

    hipMemsetAsync(cnt, 0, (size_t)NNODES * cstride * sizeof(int), stream);
    prep_kernel<<<GEMM_NB, 256, 0, stream>>>(rows, cols, vals, cnt, edata, ES, EPB, cstride, x, w, h);
    gather_kernel<<<(NNODES + RPB - 1) / RPB, 256, 0, stream>>>(h, cnt, edata, vals, bias, out, cstride, ES);
}